// Round 11
// baseline (358.955 us; speedup 1.0000x reference)
//
#include <hip/hip_runtime.h>
#include <hip/hip_bf16.h>

#define NB 4
#define NT 2048
#define DM 1024
#define DH 64

#define NBLK 512
#define CHUNK 5
#define SLOTS 7
#define PER_B 119          // sum over qb of ceil((qb+1)/5)
#define ATTN_TASKS 476     // 4 * PER_B

typedef __attribute__((ext_vector_type(8))) short bf16x8;
typedef __attribute__((ext_vector_type(4))) float f32x4;
typedef unsigned short u16;
typedef unsigned int u32;

static __device__ __forceinline__ u16 f2b(float f) {
    __hip_bfloat16 h = __float2bfloat16(f);
    return __builtin_bit_cast(u16, h);
}
static __device__ __forceinline__ float b2f(u16 h) {
    return __builtin_bit_cast(float, (u32)h << 16);
}
static __device__ __forceinline__ void gld16(const void* g, void* l) {
    __builtin_amdgcn_global_load_lds((const __attribute__((address_space(1))) void*)g,
                                     (__attribute__((address_space(3))) void*)l, 16, 0, 0);
}
#define BAR() __builtin_amdgcn_s_barrier()
#define SBAR() __builtin_amdgcn_sched_barrier(0)

// Grid-wide barrier: all NBLK blocks co-resident (LDS 48KB -> 3 blk/CU;
// even 256 VGPR -> 2 blk/CU x 256 CU = 512). syncthreads drains each wave's
// stores (vmcnt0); threadfence = agent fence (L2 wb/inv) for cross-XCD vis.
static __device__ __forceinline__ void gbar(u32* cnt, u32 nblk) {
    __syncthreads();
    __threadfence();
    if (threadIdx.x == 0) {
        __hip_atomic_fetch_add(cnt, 1u, __ATOMIC_ACQ_REL, __HIP_MEMORY_SCOPE_AGENT);
        while (__hip_atomic_load(cnt, __ATOMIC_RELAXED, __HIP_MEMORY_SCOPE_AGENT) < nblk)
            __builtin_amdgcn_s_sleep(1);
    }
    __syncthreads();
    __threadfence();
}

__global__ __launch_bounds__(256) void mega(
    const float* __restrict__ x, const float* __restrict__ WQ,
    const float* __restrict__ WK, const float* __restrict__ WV,
    u16* __restrict__ Qb, u16* __restrict__ Kb, u16* __restrict__ Vt,
    u16* __restrict__ wt, u16* __restrict__ pOt, float* __restrict__ pml,
    float* __restrict__ out, u32* __restrict__ cnt)
{
    __shared__ __align__(16) char smem[49152];
    const int tid = threadIdx.x, lane = tid & 63, w = tid >> 6;
    const int l15 = lane & 15, g = lane >> 4;

    // ================= P0: Wt[which][d][k] <- W[k][d] (48 tasks) ==========
    if (blockIdx.x < 48) {
        u16 (*tl)[68] = (u16(*)[68])smem;
        const int which = blockIdx.x / 16, kt = blockIdx.x % 16;
        const float* W = (which == 0) ? WQ : (which == 1) ? WK : WV;
        #pragma unroll
        for (int i = 0; i < 4; ++i) {
            int r = (tid >> 4) + i * 16;
            int c = (tid & 15) * 4;
            float4 v = *(const float4*)&W[(size_t)(kt * 64 + r) * DH + c];
            tl[r][c] = f2b(v.x); tl[r][c + 1] = f2b(v.y);
            tl[r][c + 2] = f2b(v.z); tl[r][c + 3] = f2b(v.w);
        }
        __syncthreads();
        int d = tid >> 2, kc = (tid & 3) * 16;
        u16 buf[16];
        #pragma unroll
        for (int j = 0; j < 16; ++j) buf[j] = tl[kc + j][d];
        u16* dst = wt + which * 65536 + d * 1024 + kt * 64 + kc;
        *(uint4*)dst = *(uint4*)&buf[0];
        *(uint4*)(dst + 8) = *(uint4*)&buf[8];
    }
    gbar(cnt + 0, NBLK);

    // ================= P1: QKV GEMM (384 tasks, R6 body) ===================
    if (blockIdx.x < 384) {
        float (*xs)[4096] = (float(*)[4096])smem;            // 32 KB
        u16 (*wsm)[4096] = (u16(*)[4096])(smem + 32768);     // 16 KB
        const int task = blockIdx.x;
        const int which = task >> 7;
        const int row0 = (task & 127) * 64;
        const u16* Wg = wt + which * 65536;

        auto stage = [&](int kt, int bi) {
            #pragma unroll
            for (int i = 0; i < 4; ++i) {
                u32 D = (u32)(w * 4096 + i * 1024 + lane * 16);
                u32 r = D >> 8, c = D & 255;
                u32 cs = c ^ ((r & 7) << 5);
                gld16(x + (size_t)(row0 + r) * DM + kt * 64 + (cs >> 2),
                      (char*)&xs[bi][0] + w * 4096 + i * 1024);
            }
            #pragma unroll
            for (int i = 0; i < 2; ++i) {
                u32 D = (u32)(w * 2048 + i * 1024 + lane * 16);
                u32 r = D >> 7, c = D & 127;
                u32 cs = c ^ ((r & 7) << 4);
                gld16(Wg + (size_t)r * 1024 + kt * 64 + (cs >> 1),
                      (char*)&wsm[bi][0] + w * 2048 + i * 1024);
            }
        };

        f32x4 acc[4];
        #pragma unroll
        for (int i = 0; i < 4; ++i) acc[i] = {0.f, 0.f, 0.f, 0.f};

        stage(0, 0);
        const int arow = w * 16 + l15;
        #pragma unroll
        for (int kt = 0; kt < 16; ++kt) {
            if (kt < 15) {
                stage(kt + 1, (kt + 1) & 1);
                asm volatile("s_waitcnt vmcnt(6)" ::: "memory");
            } else {
                asm volatile("s_waitcnt vmcnt(0)" ::: "memory");
            }
            BAR();
            SBAR();
            const char* xb = (const char*)&xs[kt & 1][0];
            const char* wb = (const char*)&wsm[kt & 1][0];
            #pragma unroll
            for (int ks = 0; ks < 2; ++ks) {
                u32 abase = (u32)(arow * 256 + ks * 128 + g * 32);
                f32x4 a0 = *(const f32x4*)(xb + (abase ^ ((arow & 7) << 5)));
                f32x4 a1 = *(const f32x4*)(xb + ((abase + 16) ^ ((arow & 7) << 5)));
                bf16x8 afrag;
                #pragma unroll
                for (int e = 0; e < 4; ++e) afrag[e] = (short)f2b(a0[e]);
                #pragma unroll
                for (int e = 0; e < 4; ++e) afrag[4 + e] = (short)f2b(a1[e]);
                __builtin_amdgcn_s_setprio(1);
                #pragma unroll
                for (int nt = 0; nt < 4; ++nt) {
                    int brow = nt * 16 + l15;
                    u32 bb = (u32)(brow * 128 + ks * 64 + g * 16);
                    bf16x8 bfrag = *(const bf16x8*)(wb + (bb ^ ((brow & 7) << 4)));
                    acc[nt] = __builtin_amdgcn_mfma_f32_16x16x32_bf16(afrag, bfrag, acc[nt], 0, 0, 0);
                }
                __builtin_amdgcn_s_setprio(0);
            }
            BAR();
        }
        #pragma unroll
        for (int nt = 0; nt < 4; ++nt) {
            int dcol = nt * 16 + l15;
            #pragma unroll
            for (int r = 0; r < 4; ++r) {
                int row = row0 + w * 16 + g * 4 + r;
                float v = acc[nt][r];
                if (which == 0)      Qb[(size_t)row * DH + dcol] = f2b(v * 0.125f);
                else if (which == 1) Kb[(size_t)row * DH + dcol] = f2b(v);
                else { int bb2 = row >> 11, t = row & 2047;
                       Vt[(size_t)bb2 * DH * NT + (size_t)dcol * NT + t] = f2b(v); }
            }
        }
    }
    gbar(cnt + 1, NBLK);

    // ================= P2: flash attention (476 tasks, R6 body) ============
    if (blockIdx.x < ATTN_TASKS) {
        u16 (*k_lds)[4096] = (u16(*)[4096])smem;             // 16 KB
        u16 (*v_lds)[4096] = (u16(*)[4096])(smem + 16384);   // 16 KB
        f32x4 (*p_lds)[128] = (f32x4(*)[128])(smem + 32768); //  8 KB

        int flat = blockIdx.x;
        const int b = flat / PER_B;
        int rem = flat - b * PER_B;
        int qb = 0, nc;
        for (;;) { nc = (qb + CHUNK) / CHUNK; if (rem < nc) break; rem -= nc; ++qb; }
        const int chunk = rem;
        const int t0 = chunk * CHUNK;
        const int t1 = min(t0 + CHUNK, qb + 1);
        const int q0 = qb * 64;

        const u16* Qg = Qb + ((size_t)b * NT + q0 + w * 16) * DH;
        const u16* Kg = Kb + (size_t)b * NT * DH;
        const u16* Vg = Vt + (size_t)b * DH * NT;

        auto stage = [&](int t, int bi) {
            const int j0 = t * 64;
            #pragma unroll
            for (int i = 0; i < 2; ++i) {
                u32 D = (u32)(w * 2048 + i * 1024 + lane * 16);
                u32 r = D >> 7, c = D & 127;
                u32 cs = c ^ ((r & 7) << 4);
                gld16(Kg + (size_t)(j0 + r) * DH + (cs >> 1),
                      (char*)&k_lds[bi][0] + w * 2048 + i * 1024);
                gld16(Vg + (size_t)r * NT + j0 + (cs >> 1),
                      (char*)&v_lds[bi][0] + w * 2048 + i * 1024);
            }
        };
        stage(t0, 0);

        bf16x8 qf[2];
        qf[0] = *(const bf16x8*)(Qg + l15 * DH + g * 8);
        qf[1] = *(const bf16x8*)(Qg + l15 * DH + 32 + g * 8);

        float m_run = -INFINITY, l_run = 0.f;
        f32x4 oacc[4];
        #pragma unroll
        for (int nt = 0; nt < 4; ++nt) oacc[nt] = {0.f, 0.f, 0.f, 0.f};

        char* pw = (char*)&p_lds[w][0];
        const int swz = (l15 & 7) << 4;

        for (int t = t0; t < t1; ++t) {
            const int cur = (t - t0) & 1;
            if (t + 1 < t1) {
                stage(t + 1, cur ^ 1);
                asm volatile("s_waitcnt vmcnt(4)" ::: "memory");
            } else {
                asm volatile("s_waitcnt vmcnt(0)" ::: "memory");
            }
            BAR();
            SBAR();
            const char* kb = (const char*)&k_lds[cur][0];
            const char* vb = (const char*)&v_lds[cur][0];

            f32x4 sacc[4];
            #pragma unroll
            for (int nt = 0; nt < 4; ++nt) sacc[nt] = {0.f, 0.f, 0.f, 0.f};
            __builtin_amdgcn_s_setprio(1);
            #pragma unroll
            for (int ks = 0; ks < 2; ++ks) {
                #pragma unroll
                for (int nt = 0; nt < 4; ++nt) {
                    int arow = nt * 16 + l15;
                    u32 aa = (u32)(arow * 128 + ks * 64 + g * 16);
                    bf16x8 kf = *(const bf16x8*)(kb + (aa ^ ((arow & 7) << 4)));
                    sacc[nt] = __builtin_amdgcn_mfma_f32_16x16x32_bf16(kf, qf[ks], sacc[nt], 0, 0, 0);
                }
            }
            __builtin_amdgcn_s_setprio(0);
            if (t == qb) {
                const int q_local = w * 16 + l15;
                #pragma unroll
                for (int nt = 0; nt < 4; ++nt)
                    #pragma unroll
                    for (int r = 0; r < 4; ++r)
                        if (nt * 16 + g * 4 + r > q_local) sacc[nt][r] = -1e30f;
            }
            float mx = -INFINITY;
            #pragma unroll
            for (int nt = 0; nt < 4; ++nt) {
                float a = fmaxf(fmaxf(sacc[nt][0], sacc[nt][1]),
                                fmaxf(sacc[nt][2], sacc[nt][3]));
                mx = fmaxf(mx, a);
            }
            mx = fmaxf(mx, __shfl_xor(mx, 16));
            mx = fmaxf(mx, __shfl_xor(mx, 32));
            const float m_new = fmaxf(m_run, mx);
            const float alpha = __expf(m_run - m_new);
            float p[4][4];
            float ps = 0.f;
            #pragma unroll
            for (int nt = 0; nt < 4; ++nt)
                #pragma unroll
                for (int r = 0; r < 4; ++r) {
                    float pv = __expf(sacc[nt][r] - m_new);
                    p[nt][r] = pv; ps += pv;
                }
            ps += __shfl_xor(ps, 16);
            ps += __shfl_xor(ps, 32);
            l_run = l_run * alpha + ps;
            m_run = m_new;
            #pragma unroll
            for (int nt = 0; nt < 4; ++nt)
                #pragma unroll
                for (int r = 0; r < 4; ++r) oacc[nt][r] *= alpha;

            #pragma unroll
            for (int nt = 0; nt < 4; ++nt) {
                uint2 pk;
                pk.x = (u32)f2b(p[nt][0]) | ((u32)f2b(p[nt][1]) << 16);
                pk.y = (u32)f2b(p[nt][2]) | ((u32)f2b(p[nt][3]) << 16);
                u32 a = (u32)((l15 * 128 + nt * 32 + g * 8) ^ swz);
                *(uint2*)(pw + a) = pk;
            }
            bf16x8 pb_[2];
            #pragma unroll
            for (int ks = 0; ks < 2; ++ks)
                pb_[ks] = *(const bf16x8*)(pw + ((u32)(l15 * 128 + ks * 64 + g * 16) ^ swz));

            __builtin_amdgcn_s_setprio(1);
            #pragma unroll
            for (int ks = 0; ks < 2; ++ks) {
                #pragma unroll
                for (int nt = 0; nt < 4; ++nt) {
                    int arow = nt * 16 + l15;
                    u32 aa = (u32)(arow * 128 + ks * 64 + g * 16);
                    bf16x8 vf = *(const bf16x8*)(vb + (aa ^ ((arow & 7) << 4)));
                    oacc[nt] = __builtin_amdgcn_mfma_f32_16x16x32_bf16(vf, pb_[ks], oacc[nt], 0, 0, 0);
                }
            }
            __builtin_amdgcn_s_setprio(0);
            BAR();
        }

        const int slot = (b * 32 + qb) * SLOTS + chunk;
        u16* Op = pOt + (size_t)slot * 4096;
        #pragma unroll
        for (int nt = 0; nt < 4; ++nt)
            #pragma unroll
            for (int r = 0; r < 4; ++r)
                Op[(nt * 16 + g * 4 + r) * 64 + w * 16 + l15] = f2b(oacc[nt][r]);
        if (g == 0) {
            float* mlp = pml + (size_t)slot * 128;
            mlp[(w * 16 + l15) * 2]     = m_run;
            mlp[(w * 16 + l15) * 2 + 1] = l_run;
        }
    }
    gbar(cnt + 2, NBLK);

    // ================= P3: merge (128 tasks) ===============================
    if (blockIdx.x < 128) {
        float (*tl)[65] = (float(*)[65])smem;                // 16.6 KB
        const int bq = blockIdx.x;
        const int b = bq >> 5, qb = bq & 31;
        const int nc = (qb + CHUNK) / CHUNK;
        const int base = bq * SLOTS;
        const int q = tid & 63, ds = tid >> 6;

        float m = -INFINITY;
        for (int c = 0; c < nc; ++c)
            m = fmaxf(m, pml[(size_t)(base + c) * 128 + q * 2]);
        float lsum = 0.f;
        float acc[16];
        #pragma unroll
        for (int i = 0; i < 16; ++i) acc[i] = 0.f;
        for (int c = 0; c < nc; ++c) {
            const float mc = pml[(size_t)(base + c) * 128 + q * 2];
            const float lc = pml[(size_t)(base + c) * 128 + q * 2 + 1];
            const float wc = __expf(mc - m);
            lsum += wc * lc;
            const u16* Op = pOt + (size_t)(base + c) * 4096;
            #pragma unroll
            for (int i = 0; i < 16; ++i)
                acc[i] += wc * b2f(Op[(ds * 16 + i) * 64 + q]);
        }
        const float inv = 1.f / lsum;
        #pragma unroll
        for (int i = 0; i < 16; ++i) tl[q][ds * 16 + i] = acc[i] * inv;
        __syncthreads();
        const int q2 = tid >> 2, dc = tid & 3;
        float* orow = out + ((size_t)b * NT + qb * 64 + q2) * 64 + dc * 16;
        #pragma unroll
        for (int j4 = 0; j4 < 4; ++j4) {
            float4 v = { tl[q2][dc * 16 + j4 * 4 + 0], tl[q2][dc * 16 + j4 * 4 + 1],
                         tl[q2][dc * 16 + j4 * 4 + 2], tl[q2][dc * 16 + j4 * 4 + 3] };
            *(float4*)&orow[j4 * 4] = v;
        }
    }
}

extern "C" void kernel_launch(void* const* d_in, const int* in_sizes, int n_in,
                              void* d_out, int out_size, void* d_ws, size_t ws_size,
                              hipStream_t stream) {
    const float* x  = (const float*)d_in[0];
    const float* WQ = (const float*)d_in[1];
    const float* WK = (const float*)d_in[2];
    const float* WV = (const float*)d_in[3];
    float* out = (float*)d_out;

    char* ws = (char*)d_ws;
    u32*   cnt = (u32*)ws;                          // 3 barrier counters
    u16*   Qb  = (u16*)(ws + 4096);                 // 1 MB
    u16*   Kb  = (u16*)(ws + 4096 + 1048576);       // 1 MB
    u16*   Vt  = (u16*)(ws + 4096 + 2097152);       // 1 MB
    u16*   Wt  = (u16*)(ws + 4096 + 3145728);       // 384 KB
    u16*   pOt = (u16*)(ws + 4096 + 3538944);       // 896 slots * 8 KB = 7 MB
    float* pml = (float*)(ws + 4096 + 3538944 + 7340032);  // 448 KB

    hipMemsetAsync(cnt, 0, 64, stream);             // zero barrier counters
    mega<<<NBLK, 256, 0, stream>>>(x, WQ, WK, WV, Qb, Kb, Vt, Wt, pOt, pml, out, cnt);
}

// Round 12
// 190.678 us; speedup vs baseline: 1.8825x; 1.8825x over previous
//
#include <hip/hip_runtime.h>
#include <hip/hip_bf16.h>

#define NB 4
#define NT 2048
#define DM 1024
#define DH 64
#define CHUNK 6
#define SLOTS 6

typedef __attribute__((ext_vector_type(8))) short bf16x8;
typedef __attribute__((ext_vector_type(4))) float f32x4;
typedef unsigned short u16;
typedef unsigned int u32;

static __device__ __forceinline__ u16 f2b(float f) {
    __hip_bfloat16 h = __float2bfloat16(f);
    return __builtin_bit_cast(u16, h);
}
static __device__ __forceinline__ float b2f(u16 h) {
    return __builtin_bit_cast(float, (u32)h << 16);
}
// global -> LDS DMA, 16B per lane. lds ptr must be wave-uniform (HW adds lane*16).
static __device__ __forceinline__ void gld16(const void* g, void* l) {
    __builtin_amdgcn_global_load_lds((const __attribute__((address_space(1))) void*)g,
                                     (__attribute__((address_space(3))) void*)l, 16, 0, 0);
}
#define BAR() __builtin_amdgcn_s_barrier()
#define SBAR() __builtin_amdgcn_sched_barrier(0)

// ---------------------------------------------------------------------------
// Wt[dd][k] bf16 <- W[k][d] fp32 (dd = which*64 + d), via LDS transpose.
// grid (16, 3)
// ---------------------------------------------------------------------------
__global__ __launch_bounds__(256) void wt_conv(
    const float* __restrict__ WQ, const float* __restrict__ WK,
    const float* __restrict__ WV, u16* __restrict__ wt)
{
    __shared__ u16 tl[64][68];
    const int which = blockIdx.y, kt = blockIdx.x;
    const float* W = (which == 0) ? WQ : (which == 1) ? WK : WV;
    #pragma unroll
    for (int i = 0; i < 4; ++i) {
        int r = (threadIdx.x >> 4) + i * 16;         // k-local
        int c = (threadIdx.x & 15) * 4;              // d
        float4 v = *(const float4*)&W[(size_t)(kt * 64 + r) * DH + c];
        tl[r][c] = f2b(v.x); tl[r][c + 1] = f2b(v.y);
        tl[r][c + 2] = f2b(v.z); tl[r][c + 3] = f2b(v.w);
    }
    __syncthreads();
    int d = threadIdx.x >> 2, kc = (threadIdx.x & 3) * 16;
    u16 buf[16];
    #pragma unroll
    for (int j = 0; j < 16; ++j) buf[j] = tl[kc + j][d];
    u16* dst = wt + (which * 64 + d) * 1024 + kt * 64 + kc;
    *(uint4*)dst = *(uint4*)&buf[0];
    *(uint4*)(dst + 8) = *(uint4*)&buf[8];
}

// ---------------------------------------------------------------------------
// QKV GEMM, fused Q|K|V (N=192) + split-K x2. grid 256 = rb(128) x kh(2):
// block computes fp32 partial [64 rows x 192 cols] over its 512-k half.
// BK=32 steps (x tile 8KB fp32, W tile 12KB bf16), 3 buffers, depth-2
// counted-vmcnt pipeline (5 DMA/wave/stage; vmcnt(10)/(5)/(0)).
// Last-block-out atomic fixup sums the two k-halves and writes bf16
// Qb (x0.125), Kb, Vt (transposed).
// ---------------------------------------------------------------------------
__global__ __launch_bounds__(256) void qkv2(
    const float* __restrict__ x, const u16* __restrict__ wt,
    float* __restrict__ pP, int* __restrict__ qcnt,
    u16* __restrict__ Qb, u16* __restrict__ Kb, u16* __restrict__ Vt)
{
    __shared__ float xs[3][2048];     // [64 r][32 k] fp32, swz ^((r&7)<<4)
    __shared__ u16 wsm[3][6144];      // [192 dd][32 k] bf16, linear (64B rows)
    __shared__ int bcast;
    const int tid = threadIdx.x, lane = tid & 63, w = tid >> 6;
    const int l15 = lane & 15, g = lane >> 4;
    const int rb = blockIdx.x >> 1, kh = blockIdx.x & 1;
    const int row0 = rb * 64, k0 = kh * 512;

    auto stage = [&](int s, int bi) {
        const int kk = k0 + s * 32;
        #pragma unroll
        for (int i = 0; i < 2; ++i) {             // x: 8KB, rows 128B
            u32 D = (u32)(w * 2048 + i * 1024 + lane * 16);
            u32 r = D >> 7, c = D & 127;
            u32 cs = c ^ ((r & 7) << 4);
            gld16(x + (size_t)(row0 + r) * DM + kk + (cs >> 2),
                  (char*)&xs[bi][0] + w * 2048 + i * 1024);
        }
        #pragma unroll
        for (int i = 0; i < 3; ++i) {             // W: 12KB, rows 64B
            u32 D = (u32)(w * 3072 + i * 1024 + lane * 16);
            u32 r = D >> 6, c = D & 63;
            gld16(wt + (size_t)r * 1024 + kk + (c >> 1),
                  (char*)&wsm[bi][0] + w * 3072 + i * 1024);
        }
    };

    f32x4 acc[12];
    #pragma unroll
    for (int i = 0; i < 12; ++i) acc[i] = {0.f, 0.f, 0.f, 0.f};

    stage(0, 0);
    stage(1, 1);

    const int arow = w * 16 + l15;
    const u32 sw = (u32)((arow & 7) << 4);
    #pragma unroll
    for (int s = 0; s < 16; ++s) {
        if (s + 2 < 16) stage(s + 2, (s + 2) % 3);
        if (s < 14)       asm volatile("s_waitcnt vmcnt(10)" ::: "memory");
        else if (s == 14) asm volatile("s_waitcnt vmcnt(5)" ::: "memory");
        else              asm volatile("s_waitcnt vmcnt(0)" ::: "memory");
        BAR();                                    // publish buf[s%3]
        SBAR();
        const char* xb = (const char*)&xs[s % 3][0];
        const char* wb = (const char*)&wsm[s % 3][0];
        u32 ab = (u32)(arow * 128 + g * 32);
        f32x4 a0 = *(const f32x4*)(xb + (ab ^ sw));
        f32x4 a1 = *(const f32x4*)(xb + ((ab + 16) ^ sw));
        bf16x8 afrag;
        #pragma unroll
        for (int e = 0; e < 4; ++e) afrag[e] = (short)f2b(a0[e]);
        #pragma unroll
        for (int e = 0; e < 4; ++e) afrag[4 + e] = (short)f2b(a1[e]);
        __builtin_amdgcn_s_setprio(1);
        #pragma unroll
        for (int nt = 0; nt < 12; ++nt) {
            bf16x8 bfrag = *(const bf16x8*)(wb + ((nt * 16 + l15) * 64 + g * 16));
            acc[nt] = __builtin_amdgcn_mfma_f32_16x16x32_bf16(afrag, bfrag, acc[nt], 0, 0, 0);
        }
        __builtin_amdgcn_s_setprio(0);
        BAR();                                    // release buf[s%3]
    }

    // ---- store fp32 partial [row 64][col 192] ----
    float* myp = pP + (size_t)(rb * 2 + kh) * 12288;
    #pragma unroll
    for (int nt = 0; nt < 12; ++nt)
        #pragma unroll
        for (int r = 0; r < 4; ++r)
            myp[(w * 16 + g * 4 + r) * 192 + nt * 16 + l15] = acc[nt][r];
    __threadfence();
    __syncthreads();
    if (tid == 0) bcast = atomicAdd(&qcnt[rb], 1);
    __syncthreads();
    if (bcast == 0) return;                       // partner will finish
    __threadfence();

    // ---- last block: add partner partial, write final bf16 outputs ----
    const float* op = pP + (size_t)(rb * 2 + (kh ^ 1)) * 12288;
    #pragma unroll
    for (int nt = 0; nt < 12; ++nt)
        #pragma unroll
        for (int r = 0; r < 4; ++r)
            acc[nt][r] += op[(w * 16 + g * 4 + r) * 192 + nt * 16 + l15];
    #pragma unroll
    for (int nt = 0; nt < 12; ++nt) {
        const int which = nt >> 2;
        const int dcol = (nt & 3) * 16 + l15;
        #pragma unroll
        for (int r = 0; r < 4; ++r) {
            int row = row0 + w * 16 + g * 4 + r;
            float v = acc[nt][r];
            if (which == 0)      Qb[(size_t)row * DH + dcol] = f2b(v * 0.125f);
            else if (which == 1) Kb[(size_t)row * DH + dcol] = f2b(v);
            else { int bb2 = row >> 11, t = row & 2047;
                   Vt[(size_t)bb2 * DH * NT + (size_t)dcol * NT + t] = f2b(v); }
        }
    }
}

// ---------------------------------------------------------------------------
// Flash attention (R6 body) + fused merge via last-block-out fixup.
// 4 waves x 16 q (QBLK=64), KVBLK=64, 2-buf DMA counted vmcnt, swapped-
// operand softmax. grid (102, NB); nchunks(qb) = ceil((qb+1)/6).
// Last chunk-block of each (b,qb) merges all partials and writes fp32 out.
// ---------------------------------------------------------------------------
__global__ __launch_bounds__(256) void attn(
    const u16* __restrict__ Qb, const u16* __restrict__ Kb,
    const u16* __restrict__ Vt, u16* __restrict__ pOt, float* __restrict__ pml,
    int* __restrict__ acnt, float* __restrict__ out)
{
    __shared__ __align__(16) char smem[40960];    // k(16K) | v(16K) | p(8K)
    __shared__ int bcast;
    u16 (*k_lds)[4096] = (u16(*)[4096])smem;
    u16 (*v_lds)[4096] = (u16(*)[4096])(smem + 16384);
    f32x4* p_lds = (f32x4*)(smem + 32768);

    const int tid = threadIdx.x, lane = tid & 63, w = tid >> 6;
    const int l15 = lane & 15, g = lane >> 4;
    const int b = blockIdx.y;

    int flat = blockIdx.x, qb = 0, nc;
    for (;;) { nc = (qb + CHUNK) / CHUNK; if (flat < nc) break; flat -= nc; ++qb; }
    const int chunk = flat;
    const int t0 = chunk * CHUNK;
    const int t1 = min(t0 + CHUNK, qb + 1);
    const int q0 = qb * 64;

    const u16* Qg = Qb + ((size_t)b * NT + q0 + w * 16) * DH;
    const u16* Kg = Kb + (size_t)b * NT * DH;
    const u16* Vg = Vt + (size_t)b * DH * NT;

    auto stage = [&](int t, int bi) {
        const int j0 = t * 64;
        #pragma unroll
        for (int i = 0; i < 2; ++i) {
            u32 D = (u32)(w * 2048 + i * 1024 + lane * 16);
            u32 r = D >> 7, c = D & 127;
            u32 cs = c ^ ((r & 7) << 4);
            gld16(Kg + (size_t)(j0 + r) * DH + (cs >> 1),
                  (char*)&k_lds[bi][0] + w * 2048 + i * 1024);
            gld16(Vg + (size_t)r * NT + j0 + (cs >> 1),
                  (char*)&v_lds[bi][0] + w * 2048 + i * 1024);
        }
    };
    stage(t0, 0);

    bf16x8 qf[2];
    qf[0] = *(const bf16x8*)(Qg + l15 * DH + g * 8);
    qf[1] = *(const bf16x8*)(Qg + l15 * DH + 32 + g * 8);

    float m_run = -INFINITY, l_run = 0.f;
    f32x4 oacc[4];
    #pragma unroll
    for (int nt = 0; nt < 4; ++nt) oacc[nt] = {0.f, 0.f, 0.f, 0.f};

    char* pw = (char*)&p_lds[w * 128];
    const int swz = (l15 & 7) << 4;

    for (int t = t0; t < t1; ++t) {
        const int cur = (t - t0) & 1;
        if (t + 1 < t1) {
            stage(t + 1, cur ^ 1);
            asm volatile("s_waitcnt vmcnt(4)" ::: "memory");
        } else {
            asm volatile("s_waitcnt vmcnt(0)" ::: "memory");
        }
        BAR();
        SBAR();
        const char* kb = (const char*)&k_lds[cur][0];
        const char* vb = (const char*)&v_lds[cur][0];

        f32x4 sacc[4];
        #pragma unroll
        for (int nt = 0; nt < 4; ++nt) sacc[nt] = {0.f, 0.f, 0.f, 0.f};
        __builtin_amdgcn_s_setprio(1);
        #pragma unroll
        for (int ks = 0; ks < 2; ++ks) {
            #pragma unroll
            for (int nt = 0; nt < 4; ++nt) {
                int arow = nt * 16 + l15;
                u32 aa = (u32)(arow * 128 + ks * 64 + g * 16);
                bf16x8 kf = *(const bf16x8*)(kb + (aa ^ ((arow & 7) << 4)));
                sacc[nt] = __builtin_amdgcn_mfma_f32_16x16x32_bf16(kf, qf[ks], sacc[nt], 0, 0, 0);
            }
        }
        __builtin_amdgcn_s_setprio(0);
        if (t == qb) {
            const int q_local = w * 16 + l15;
            #pragma unroll
            for (int nt = 0; nt < 4; ++nt)
                #pragma unroll
                for (int r = 0; r < 4; ++r)
                    if (nt * 16 + g * 4 + r > q_local) sacc[nt][r] = -1e30f;
        }
        float mx = -INFINITY;
        #pragma unroll
        for (int nt = 0; nt < 4; ++nt) {
            float a = fmaxf(fmaxf(sacc[nt][0], sacc[nt][1]),
                            fmaxf(sacc[nt][2], sacc[nt][3]));
            mx = fmaxf(mx, a);
        }
        mx = fmaxf(mx, __shfl_xor(mx, 16));
        mx = fmaxf(mx, __shfl_xor(mx, 32));
        const float m_new = fmaxf(m_run, mx);
        const float alpha = __expf(m_run - m_new);
        float p[4][4];
        float ps = 0.f;
        #pragma unroll
        for (int nt = 0; nt < 4; ++nt)
            #pragma unroll
            for (int r = 0; r < 4; ++r) {
                float pv = __expf(sacc[nt][r] - m_new);
                p[nt][r] = pv; ps += pv;
            }
        ps += __shfl_xor(ps, 16);
        ps += __shfl_xor(ps, 32);
        l_run = l_run * alpha + ps;
        m_run = m_new;
        #pragma unroll
        for (int nt = 0; nt < 4; ++nt)
            #pragma unroll
            for (int r = 0; r < 4; ++r) oacc[nt][r] *= alpha;

        #pragma unroll
        for (int nt = 0; nt < 4; ++nt) {
            uint2 pk;
            pk.x = (u32)f2b(p[nt][0]) | ((u32)f2b(p[nt][1]) << 16);
            pk.y = (u32)f2b(p[nt][2]) | ((u32)f2b(p[nt][3]) << 16);
            u32 a = (u32)((l15 * 128 + nt * 32 + g * 8) ^ swz);
            *(uint2*)(pw + a) = pk;
        }
        bf16x8 pb_[2];
        #pragma unroll
        for (int ks = 0; ks < 2; ++ks)
            pb_[ks] = *(const bf16x8*)(pw + ((u32)(l15 * 128 + ks * 64 + g * 16) ^ swz));

        __builtin_amdgcn_s_setprio(1);
        #pragma unroll
        for (int ks = 0; ks < 2; ++ks) {
            #pragma unroll
            for (int nt = 0; nt < 4; ++nt) {
                int arow = nt * 16 + l15;
                u32 aa = (u32)(arow * 128 + ks * 64 + g * 16);
                bf16x8 vf = *(const bf16x8*)(vb + (aa ^ ((arow & 7) << 4)));
                oacc[nt] = __builtin_amdgcn_mfma_f32_16x16x32_bf16(vf, pb_[ks], oacc[nt], 0, 0, 0);
            }
        }
        __builtin_amdgcn_s_setprio(0);
        BAR();
    }

    // ---- write partials (O^T bf16, m/l f32) ----
    const int bq = b * 32 + qb;
    const int slot = bq * SLOTS + chunk;
    u16* Op = pOt + (size_t)slot * 4096;
    #pragma unroll
    for (int nt = 0; nt < 4; ++nt)
        #pragma unroll
        for (int r = 0; r < 4; ++r)
            Op[(nt * 16 + g * 4 + r) * 64 + w * 16 + l15] = f2b(oacc[nt][r]);
    if (g == 0) {
        float* mlp = pml + (size_t)slot * 128;
        mlp[(w * 16 + l15) * 2]     = m_run;
        mlp[(w * 16 + l15) * 2 + 1] = l_run;
    }
    __threadfence();
    __syncthreads();
    if (tid == 0) bcast = atomicAdd(&acnt[bq], 1);
    __syncthreads();
    if (bcast != nc - 1) return;                  // not the last chunk-block
    __threadfence();

    // ---- last block: merge all chunks, write fp32 out [q][d] ----
    float (*tl)[65] = (float(*)[65])smem;         // reuse LDS (compute done)
    const int base = bq * SLOTS;
    const int q = tid & 63, ds = tid >> 6;
    float m = -INFINITY;
    for (int c = 0; c < nc; ++c)
        m = fmaxf(m, pml[(size_t)(base + c) * 128 + q * 2]);
    float lsum = 0.f;
    float acc[16];
    #pragma unroll
    for (int i = 0; i < 16; ++i) acc[i] = 0.f;
    for (int c = 0; c < nc; ++c) {
        const float mc = pml[(size_t)(base + c) * 128 + q * 2];
        const float lc = pml[(size_t)(base + c) * 128 + q * 2 + 1];
        const float wc = __expf(mc - m);
        lsum += wc * lc;
        const u16* Oc = pOt + (size_t)(base + c) * 4096;
        #pragma unroll
        for (int i = 0; i < 16; ++i)
            acc[i] += wc * b2f(Oc[(ds * 16 + i) * 64 + q]);
    }
    const float inv = 1.f / lsum;
    #pragma unroll
    for (int i = 0; i < 16; ++i) tl[q][ds * 16 + i] = acc[i] * inv;
    __syncthreads();
    const int q2 = tid >> 2, dc = tid & 3;
    float* orow = out + ((size_t)b * NT + qb * 64 + q2) * 64 + dc * 16;
    #pragma unroll
    for (int j4 = 0; j4 < 4; ++j4) {
        float4 v = { tl[q2][dc * 16 + j4 * 4 + 0], tl[q2][dc * 16 + j4 * 4 + 1],
                     tl[q2][dc * 16 + j4 * 4 + 2], tl[q2][dc * 16 + j4 * 4 + 3] };
        *(float4*)&orow[j4 * 4] = v;
    }
}

extern "C" void kernel_launch(void* const* d_in, const int* in_sizes, int n_in,
                              void* d_out, int out_size, void* d_ws, size_t ws_size,
                              hipStream_t stream) {
    const float* x  = (const float*)d_in[0];
    const float* WQ = (const float*)d_in[1];
    const float* WK = (const float*)d_in[2];
    const float* WV = (const float*)d_in[3];
    float* out = (float*)d_out;

    char* ws = (char*)d_ws;
    int*   qcnt = (int*)ws;                        // 128 ints
    int*   acnt = (int*)(ws + 512);                // 128 ints
    u16*   Qb   = (u16*)(ws + 4096);               // 1 MB
    u16*   Kb   = (u16*)(ws + 4096 + 1048576);     // 1 MB
    u16*   Vt   = (u16*)(ws + 4096 + 2097152);     // 1 MB
    u16*   Wt   = (u16*)(ws + 4096 + 3145728);     // 384 KB
    float* pP   = (float*)(ws + 3543040);          // 12.6 MB qkv partials
    u16*   pOt  = (u16*)(ws + 16125952);           // 6.3 MB attn partials
    float* pml  = (float*)(ws + 22417408);         // 384 KB

    hipMemsetAsync(ws, 0, 4096, stream);           // zero fixup counters

    // attn grid.x = sum over qb of ceil((qb+1)/CHUNK) = 102 for CHUNK=6
    wt_conv<<<dim3(16, 3), 256, 0, stream>>>(WQ, WK, WV, Wt);
    qkv2<<<256, 256, 0, stream>>>(x, Wt, pP, qcnt, Qb, Kb, Vt);
    attn<<<dim3(102, NB), 256, 0, stream>>>(Qb, Kb, Vt, pOt, pml, acnt, out);
}

// Round 13
// 51.856 us; speedup vs baseline: 6.9221x; 3.6770x over previous
//
#include <hip/hip_runtime.h>
#include <hip/hip_bf16.h>

#define NB 4
#define NT 2048
#define DM 1024
#define DH 64
#define CHUNK 6
#define SLOTS 6

typedef __attribute__((ext_vector_type(8))) short bf16x8;
typedef __attribute__((ext_vector_type(4))) float f32x4;
typedef unsigned short u16;
typedef unsigned int u32;

static __device__ __forceinline__ u16 f2b(float f) {
    __hip_bfloat16 h = __float2bfloat16(f);
    return __builtin_bit_cast(u16, h);
}
static __device__ __forceinline__ float b2f(u16 h) {
    return __builtin_bit_cast(float, (u32)h << 16);
}
// global -> LDS DMA, 16B per lane. lds ptr must be wave-uniform (HW adds lane*16).
static __device__ __forceinline__ void gld16(const void* g, void* l) {
    __builtin_amdgcn_global_load_lds((const __attribute__((address_space(1))) void*)g,
                                     (__attribute__((address_space(3))) void*)l, 16, 0, 0);
}
#define BAR() __builtin_amdgcn_s_barrier()
#define SBAR() __builtin_amdgcn_sched_barrier(0)

// ---------------------------------------------------------------------------
// Wt[dd][k] bf16 <- W[k][d] fp32 (dd = which*64+d), via LDS transpose.
// grid (16, 3)
// ---------------------------------------------------------------------------
__global__ __launch_bounds__(256) void wt_conv(
    const float* __restrict__ WQ, const float* __restrict__ WK,
    const float* __restrict__ WV, u16* __restrict__ wt)
{
    __shared__ u16 tl[64][68];
    const int which = blockIdx.y, kt = blockIdx.x;
    const float* W = (which == 0) ? WQ : (which == 1) ? WK : WV;
    #pragma unroll
    for (int i = 0; i < 4; ++i) {
        int r = (threadIdx.x >> 4) + i * 16;         // k-local
        int c = (threadIdx.x & 15) * 4;              // d
        float4 v = *(const float4*)&W[(size_t)(kt * 64 + r) * DH + c];
        tl[r][c] = f2b(v.x); tl[r][c + 1] = f2b(v.y);
        tl[r][c + 2] = f2b(v.z); tl[r][c + 3] = f2b(v.w);
    }
    __syncthreads();
    int d = threadIdx.x >> 2, kc = (threadIdx.x & 3) * 16;
    u16 buf[16];
    #pragma unroll
    for (int j = 0; j < 16; ++j) buf[j] = tl[kc + j][d];
    u16* dst = wt + (size_t)(which * 64 + d) * 1024 + kt * 64 + kc;
    *(uint4*)dst = *(uint4*)&buf[0];
    *(uint4*)(dst + 8) = *(uint4*)&buf[8];
}

// ---------------------------------------------------------------------------
// QKV GEMM, fused Q|K|V in ONE pass over x. grid 256: block = 32 rows x 192
// cols. BK=32, 3 LDS buffers, depth-2 counted-vmcnt pipeline (4 DMA/wave/
// stage -> vmcnt(8)/(4)/(0)). Wave w owns cols w*48..w*48+47 (3 n-frags),
// 2 m-frags. x staged fp32 swizzled; Wt staged linear (64B rows).
// ---------------------------------------------------------------------------
__global__ __launch_bounds__(256) void qkv3(
    const float* __restrict__ x, const u16* __restrict__ wt,
    u16* __restrict__ Qb, u16* __restrict__ Kb, u16* __restrict__ Vt)
{
    __shared__ float xs[3][1024];     // [32 r][32 k] fp32, rows 128B, swz
    __shared__ u16 wsm[3][6144];      // [192 dd][32 k] bf16, rows 64B, linear
    const int tid = threadIdx.x, lane = tid & 63, w = tid >> 6;
    const int l15 = lane & 15, g = lane >> 4;
    const int row0 = blockIdx.x * 32;

    auto stage = [&](int s, int bi) {
        const int kk = s * 32;
        {   // x tile: 4KB, 1 gld16/thread
            u32 D = (u32)(w * 1024 + lane * 16);
            u32 r = D >> 7, c = D & 127;
            u32 cs = c ^ ((r & 7) << 4);
            gld16(x + (size_t)(row0 + r) * DM + kk + (cs >> 2),
                  (char*)&xs[bi][0] + w * 1024);
        }
        #pragma unroll
        for (int i = 0; i < 3; ++i) {  // W tile: 12KB, 3 gld16/thread
            u32 D = (u32)(w * 3072 + i * 1024 + lane * 16);
            u32 r = D >> 6, c = D & 63;
            gld16(wt + (size_t)r * 1024 + kk + (c >> 1),
                  (char*)&wsm[bi][0] + w * 3072 + i * 1024);
        }
    };

    f32x4 acc[2][3];
    #pragma unroll
    for (int mf = 0; mf < 2; ++mf)
        #pragma unroll
        for (int nt = 0; nt < 3; ++nt) acc[mf][nt] = {0.f, 0.f, 0.f, 0.f};

    stage(0, 0);
    stage(1, 1);

    for (int s = 0; s < 32; ++s) {
        if (s + 2 < 32) stage(s + 2, (s + 2) % 3);
        if (s < 30)       asm volatile("s_waitcnt vmcnt(8)" ::: "memory");
        else if (s == 30) asm volatile("s_waitcnt vmcnt(4)" ::: "memory");
        else              asm volatile("s_waitcnt vmcnt(0)" ::: "memory");
        BAR();                                    // publish buf[s%3]
        SBAR();
        const char* xb = (const char*)&xs[s % 3][0];
        const char* wb = (const char*)&wsm[s % 3][0];

        bf16x8 afrag[2];
        #pragma unroll
        for (int mf = 0; mf < 2; ++mf) {
            const int arow = mf * 16 + l15;
            const u32 sw = (u32)((arow & 7) << 4);
            u32 ab = (u32)(arow * 128 + g * 32);
            f32x4 a0 = *(const f32x4*)(xb + (ab ^ sw));
            f32x4 a1 = *(const f32x4*)(xb + ((ab + 16) ^ sw));
            #pragma unroll
            for (int e = 0; e < 4; ++e) afrag[mf][e] = (short)f2b(a0[e]);
            #pragma unroll
            for (int e = 0; e < 4; ++e) afrag[mf][4 + e] = (short)f2b(a1[e]);
        }
        bf16x8 bfrag[3];
        #pragma unroll
        for (int nt = 0; nt < 3; ++nt) {
            const int dd = w * 48 + nt * 16 + l15;
            bfrag[nt] = *(const bf16x8*)(wb + dd * 64 + g * 16);
        }
        __builtin_amdgcn_s_setprio(1);
        #pragma unroll
        for (int mf = 0; mf < 2; ++mf)
            #pragma unroll
            for (int nt = 0; nt < 3; ++nt)
                acc[mf][nt] = __builtin_amdgcn_mfma_f32_16x16x32_bf16(
                    afrag[mf], bfrag[nt], acc[mf][nt], 0, 0, 0);
        __builtin_amdgcn_s_setprio(0);
        BAR();                                    // release buf[s%3]
    }

    // epilogue: C col = w*48 + nt*16 + l15, row = row0 + mf*16 + g*4 + r
    #pragma unroll
    for (int mf = 0; mf < 2; ++mf) {
        #pragma unroll
        for (int nt = 0; nt < 3; ++nt) {
            const int dcg = w * 48 + nt * 16 + l15;   // 0..191
            const int which = dcg >> 6, dcol = dcg & 63;
            #pragma unroll
            for (int r = 0; r < 4; ++r) {
                const int row = row0 + mf * 16 + g * 4 + r;
                const float v = acc[mf][nt][r];
                if (which == 0)      Qb[(size_t)row * DH + dcol] = f2b(v * 0.125f);
                else if (which == 1) Kb[(size_t)row * DH + dcol] = f2b(v);
                else { int bb2 = row >> 11, t = row & 2047;
                       Vt[(size_t)bb2 * DH * NT + (size_t)dcol * NT + t] = f2b(v); }
            }
        }
    }
}

// ---------------------------------------------------------------------------
// Flash attention (R6 body verbatim). 4 waves x 16 q (QBLK=64), KVBLK=64,
// 2-buf DMA counted vmcnt, swapped-operand in-register softmax.
// grid (102, NB); nchunks(qb) = ceil((qb+1)/6).
// ---------------------------------------------------------------------------
__global__ __launch_bounds__(256) void attn(
    const u16* __restrict__ Qb, const u16* __restrict__ Kb,
    const u16* __restrict__ Vt, u16* __restrict__ pOt, float* __restrict__ pml)
{
    __shared__ u16 k_lds[2][4096];
    __shared__ u16 v_lds[2][4096];
    __shared__ f32x4 p_lds[4][128];

    const int tid = threadIdx.x, lane = tid & 63, w = tid >> 6;
    const int l15 = lane & 15, g = lane >> 4;
    const int b = blockIdx.y;

    int flat = blockIdx.x, qb = 0, nc;
    for (;;) { nc = (qb + CHUNK) / CHUNK; if (flat < nc) break; flat -= nc; ++qb; }
    const int chunk = flat;
    const int t0 = chunk * CHUNK;
    const int t1 = min(t0 + CHUNK, qb + 1);
    const int q0 = qb * 64;

    const u16* Qg = Qb + ((size_t)b * NT + q0 + w * 16) * DH;
    const u16* Kg = Kb + (size_t)b * NT * DH;
    const u16* Vg = Vt + (size_t)b * DH * NT;

    auto stage = [&](int t, int bi) {
        const int j0 = t * 64;
        #pragma unroll
        for (int i = 0; i < 2; ++i) {
            u32 D = (u32)(w * 2048 + i * 1024 + lane * 16);
            u32 r = D >> 7, c = D & 127;
            u32 cs = c ^ ((r & 7) << 4);
            gld16(Kg + (size_t)(j0 + r) * DH + (cs >> 1),
                  (char*)&k_lds[bi][0] + w * 2048 + i * 1024);
            gld16(Vg + (size_t)r * NT + j0 + (cs >> 1),
                  (char*)&v_lds[bi][0] + w * 2048 + i * 1024);
        }
    };
    stage(t0, 0);

    bf16x8 qf[2];
    qf[0] = *(const bf16x8*)(Qg + l15 * DH + g * 8);
    qf[1] = *(const bf16x8*)(Qg + l15 * DH + 32 + g * 8);

    float m_run = -INFINITY, l_run = 0.f;
    f32x4 oacc[4];
    #pragma unroll
    for (int nt = 0; nt < 4; ++nt) oacc[nt] = {0.f, 0.f, 0.f, 0.f};

    char* pw = (char*)&p_lds[w][0];
    const int swz = (l15 & 7) << 4;

    for (int t = t0; t < t1; ++t) {
        const int cur = (t - t0) & 1;
        if (t + 1 < t1) {
            stage(t + 1, cur ^ 1);
            asm volatile("s_waitcnt vmcnt(4)" ::: "memory");
        } else {
            asm volatile("s_waitcnt vmcnt(0)" ::: "memory");
        }
        BAR();
        SBAR();
        const char* kb = (const char*)&k_lds[cur][0];
        const char* vb = (const char*)&v_lds[cur][0];

        f32x4 sacc[4];
        #pragma unroll
        for (int nt = 0; nt < 4; ++nt) sacc[nt] = {0.f, 0.f, 0.f, 0.f};
        __builtin_amdgcn_s_setprio(1);
        #pragma unroll
        for (int ks = 0; ks < 2; ++ks) {
            #pragma unroll
            for (int nt = 0; nt < 4; ++nt) {
                int arow = nt * 16 + l15;
                u32 aa = (u32)(arow * 128 + ks * 64 + g * 16);
                bf16x8 kf = *(const bf16x8*)(kb + (aa ^ ((arow & 7) << 4)));
                sacc[nt] = __builtin_amdgcn_mfma_f32_16x16x32_bf16(kf, qf[ks], sacc[nt], 0, 0, 0);
            }
        }
        __builtin_amdgcn_s_setprio(0);
        if (t == qb) {
            const int q_local = w * 16 + l15;
            #pragma unroll
            for (int nt = 0; nt < 4; ++nt)
                #pragma unroll
                for (int r = 0; r < 4; ++r)
                    if (nt * 16 + g * 4 + r > q_local) sacc[nt][r] = -1e30f;
        }
        float mx = -INFINITY;
        #pragma unroll
        for (int nt = 0; nt < 4; ++nt) {
            float a = fmaxf(fmaxf(sacc[nt][0], sacc[nt][1]),
                            fmaxf(sacc[nt][2], sacc[nt][3]));
            mx = fmaxf(mx, a);
        }
        mx = fmaxf(mx, __shfl_xor(mx, 16));
        mx = fmaxf(mx, __shfl_xor(mx, 32));
        const float m_new = fmaxf(m_run, mx);
        const float alpha = __expf(m_run - m_new);
        float p[4][4];
        float ps = 0.f;
        #pragma unroll
        for (int nt = 0; nt < 4; ++nt)
            #pragma unroll
            for (int r = 0; r < 4; ++r) {
                float pv = __expf(sacc[nt][r] - m_new);
                p[nt][r] = pv; ps += pv;
            }
        ps += __shfl_xor(ps, 16);
        ps += __shfl_xor(ps, 32);
        l_run = l_run * alpha + ps;
        m_run = m_new;
        #pragma unroll
        for (int nt = 0; nt < 4; ++nt)
            #pragma unroll
            for (int r = 0; r < 4; ++r) oacc[nt][r] *= alpha;

        #pragma unroll
        for (int nt = 0; nt < 4; ++nt) {
            uint2 pk;
            pk.x = (u32)f2b(p[nt][0]) | ((u32)f2b(p[nt][1]) << 16);
            pk.y = (u32)f2b(p[nt][2]) | ((u32)f2b(p[nt][3]) << 16);
            u32 a = (u32)((l15 * 128 + nt * 32 + g * 8) ^ swz);
            *(uint2*)(pw + a) = pk;
        }
        bf16x8 pb_[2];
        #pragma unroll
        for (int ks = 0; ks < 2; ++ks)
            pb_[ks] = *(const bf16x8*)(pw + ((u32)(l15 * 128 + ks * 64 + g * 16) ^ swz));

        __builtin_amdgcn_s_setprio(1);
        #pragma unroll
        for (int ks = 0; ks < 2; ++ks) {
            #pragma unroll
            for (int nt = 0; nt < 4; ++nt) {
                int arow = nt * 16 + l15;
                u32 aa = (u32)(arow * 128 + ks * 64 + g * 16);
                bf16x8 vf = *(const bf16x8*)(vb + (aa ^ ((arow & 7) << 4)));
                oacc[nt] = __builtin_amdgcn_mfma_f32_16x16x32_bf16(vf, pb_[ks], oacc[nt], 0, 0, 0);
            }
        }
        __builtin_amdgcn_s_setprio(0);
        BAR();
    }

    const int slot = ((b * 32 + qb)) * SLOTS + chunk;
    u16* Op = pOt + (size_t)slot * 4096;
    #pragma unroll
    for (int nt = 0; nt < 4; ++nt)
        #pragma unroll
        for (int r = 0; r < 4; ++r)
            Op[(nt * 16 + g * 4 + r) * 64 + w * 16 + l15] = f2b(oacc[nt][r]);
    if (g == 0) {
        float* mlp = pml + (size_t)slot * 128;
        mlp[(w * 16 + l15) * 2]     = m_run;
        mlp[(w * 16 + l15) * 2 + 1] = l_run;
    }
}

// ---------------------------------------------------------------------------
// Merge <=SLOTS transposed partials per (b,qb); LDS transpose; fp32 out [q][d].
// grid = NB*32 blocks.
// ---------------------------------------------------------------------------
__global__ __launch_bounds__(256) void merge(
    const u16* __restrict__ pOt, const float* __restrict__ pml,
    float* __restrict__ out)
{
    __shared__ float tl[64][65];
    const int bq = blockIdx.x;             // b*32 + qb
    const int b = bq >> 5, qb = bq & 31;
    const int nc = (qb + CHUNK) / CHUNK;
    const int base = bq * SLOTS;
    const int q = threadIdx.x & 63, ds = threadIdx.x >> 6;

    float m = -INFINITY;
    for (int c = 0; c < nc; ++c)
        m = fmaxf(m, pml[(size_t)(base + c) * 128 + q * 2]);
    float lsum = 0.f;
    float acc[16];
    #pragma unroll
    for (int i = 0; i < 16; ++i) acc[i] = 0.f;
    for (int c = 0; c < nc; ++c) {
        const float mc = pml[(size_t)(base + c) * 128 + q * 2];
        const float lc = pml[(size_t)(base + c) * 128 + q * 2 + 1];
        const float wc = __expf(mc - m);
        lsum += wc * lc;
        const u16* Op = pOt + (size_t)(base + c) * 4096;
        #pragma unroll
        for (int i = 0; i < 16; ++i)
            acc[i] += wc * b2f(Op[(ds * 16 + i) * 64 + q]);
    }
    const float inv = 1.f / lsum;
    #pragma unroll
    for (int i = 0; i < 16; ++i) tl[q][ds * 16 + i] = acc[i] * inv;
    __syncthreads();
    const int q2 = threadIdx.x >> 2, dc = threadIdx.x & 3;
    float* orow = out + ((size_t)b * NT + qb * 64 + q2) * 64 + dc * 16;
    #pragma unroll
    for (int j4 = 0; j4 < 4; ++j4) {
        float4 v = { tl[q2][dc * 16 + j4 * 4 + 0], tl[q2][dc * 16 + j4 * 4 + 1],
                     tl[q2][dc * 16 + j4 * 4 + 2], tl[q2][dc * 16 + j4 * 4 + 3] };
        *(float4*)&orow[j4 * 4] = v;
    }
}

extern "C" void kernel_launch(void* const* d_in, const int* in_sizes, int n_in,
                              void* d_out, int out_size, void* d_ws, size_t ws_size,
                              hipStream_t stream) {
    const float* x  = (const float*)d_in[0];
    const float* WQ = (const float*)d_in[1];
    const float* WK = (const float*)d_in[2];
    const float* WV = (const float*)d_in[3];
    float* out = (float*)d_out;

    char* ws = (char*)d_ws;
    u16*   Qb  = (u16*)ws;                          // 1 MB
    u16*   Kb  = (u16*)(ws + 1048576);              // 1 MB
    u16*   Vt  = (u16*)(ws + 2097152);              // 1 MB
    u16*   Wt  = (u16*)(ws + 3145728);              // 384 KB
    u16*   pOt = (u16*)(ws + 3538944);              // 768 slots * 8 KB = 6 MB
    float* pml = (float*)(ws + 3538944 + 6291456);  // 384 KB

    // attn grid.x = sum over qb of ceil((qb+1)/CHUNK) = 102 for CHUNK=6
    wt_conv<<<dim3(16, 3), 256, 0, stream>>>(WQ, WK, WV, Wt);
    qkv3<<<256, 256, 0, stream>>>(x, Wt, Qb, Kb, Vt);
    attn<<<dim3(102, NB), 256, 0, stream>>>(Qb, Kb, Vt, pOt, pml);
    merge<<<NB * 32, 256, 0, stream>>>(pOt, pml, out);
}

// Round 14
// 42.794 us; speedup vs baseline: 8.3880x; 1.2118x over previous
//
#include <hip/hip_runtime.h>
#include <hip/hip_bf16.h>

#define NB 4
#define NT 2048
#define DM 1024
#define DH 64
#define CHUNK3 3          // KV chunk in units of 128-key tiles
#define SLOTS 6

typedef __attribute__((ext_vector_type(8))) short bf16x8;
typedef __attribute__((ext_vector_type(4))) float f32x4;
typedef unsigned short u16;
typedef unsigned int u32;

static __device__ __forceinline__ u16 f2b(float f) {
    __hip_bfloat16 h = __float2bfloat16(f);
    return __builtin_bit_cast(u16, h);
}
static __device__ __forceinline__ float b2f(u16 h) {
    return __builtin_bit_cast(float, (u32)h << 16);
}
// global -> LDS DMA, 16B per lane. lds ptr must be wave-uniform (HW adds lane*16).
static __device__ __forceinline__ void gld16(const void* g, void* l) {
    __builtin_amdgcn_global_load_lds((const __attribute__((address_space(1))) void*)g,
                                     (__attribute__((address_space(3))) void*)l, 16, 0, 0);
}
#define BAR() __builtin_amdgcn_s_barrier()
#define SBAR() __builtin_amdgcn_sched_barrier(0)

// ---------------------------------------------------------------------------
// Wt[which][d][k] bf16 <- W[k][d] fp32, via LDS transpose. grid (16, 3)
// ---------------------------------------------------------------------------
__global__ __launch_bounds__(256) void wt_conv(
    const float* __restrict__ WQ, const float* __restrict__ WK,
    const float* __restrict__ WV, u16* __restrict__ wt)
{
    __shared__ u16 tl[64][68];
    const int which = blockIdx.y, kt = blockIdx.x;
    const float* W = (which == 0) ? WQ : (which == 1) ? WK : WV;
    #pragma unroll
    for (int i = 0; i < 4; ++i) {
        int r = (threadIdx.x >> 4) + i * 16;         // k-local
        int c = (threadIdx.x & 15) * 4;              // d
        float4 v = *(const float4*)&W[(size_t)(kt * 64 + r) * DH + c];
        tl[r][c] = f2b(v.x); tl[r][c + 1] = f2b(v.y);
        tl[r][c + 2] = f2b(v.z); tl[r][c + 3] = f2b(v.w);
    }
    __syncthreads();
    int d = threadIdx.x >> 2, kc = (threadIdx.x & 3) * 16;
    u16 buf[16];
    #pragma unroll
    for (int j = 0; j < 16; ++j) buf[j] = tl[kc + j][d];
    u16* dst = wt + which * 65536 + d * 1024 + kt * 64 + kc;
    *(uint4*)dst = *(uint4*)&buf[0];
    *(uint4*)(dst + 8) = *(uint4*)&buf[8];
}

// ---------------------------------------------------------------------------
// QKV GEMM (R6 champion body, verbatim). grid (128, 3): 64-row tile x one of
// Q/K/V. 2-buffer pipeline, counted vmcnt (6 DMA/wave/stage).
// ---------------------------------------------------------------------------
__global__ __launch_bounds__(256) void qkv_gemm(
    const float* __restrict__ x, const u16* __restrict__ wt,
    u16* __restrict__ Qb, u16* __restrict__ Kb, u16* __restrict__ Vt)
{
    __shared__ float xs[2][4096];     // 2 x 16 KB fp32, swizzle ^((r&7)<<5)
    __shared__ u16 wsm[2][4096];      // 2 x  8 KB bf16, swizzle ^((r&7)<<4)
    const int tid = threadIdx.x, lane = tid & 63, w = tid >> 6;
    const int l15 = lane & 15, g = lane >> 4;
    const int row0 = blockIdx.x * 64;
    const int which = blockIdx.y;
    const u16* Wg = wt + which * 65536;

    auto stage = [&](int kt, int bi) {
        #pragma unroll
        for (int i = 0; i < 4; ++i) {
            u32 D = (u32)(w * 4096 + i * 1024 + lane * 16);
            u32 r = D >> 8, c = D & 255;
            u32 cs = c ^ ((r & 7) << 5);
            gld16(x + (size_t)(row0 + r) * DM + kt * 64 + (cs >> 2),
                  (char*)&xs[bi][0] + w * 4096 + i * 1024);
        }
        #pragma unroll
        for (int i = 0; i < 2; ++i) {
            u32 D = (u32)(w * 2048 + i * 1024 + lane * 16);
            u32 r = D >> 7, c = D & 127;
            u32 cs = c ^ ((r & 7) << 4);
            gld16(Wg + (size_t)r * 1024 + kt * 64 + (cs >> 1),
                  (char*)&wsm[bi][0] + w * 2048 + i * 1024);
        }
    };

    f32x4 acc[4];
    #pragma unroll
    for (int i = 0; i < 4; ++i) acc[i] = {0.f, 0.f, 0.f, 0.f};

    stage(0, 0);

    const int arow = w * 16 + l15;
    #pragma unroll
    for (int kt = 0; kt < 16; ++kt) {
        if (kt < 15) {
            stage(kt + 1, (kt + 1) & 1);
            asm volatile("s_waitcnt vmcnt(6)" ::: "memory");
        } else {
            asm volatile("s_waitcnt vmcnt(0)" ::: "memory");
        }
        BAR();                                    // publish buf[kt&1]
        SBAR();
        const char* xb = (const char*)&xs[kt & 1][0];
        const char* wb = (const char*)&wsm[kt & 1][0];
        #pragma unroll
        for (int ks = 0; ks < 2; ++ks) {
            u32 abase = (u32)(arow * 256 + ks * 128 + g * 32);
            f32x4 a0 = *(const f32x4*)(xb + (abase ^ ((arow & 7) << 5)));
            f32x4 a1 = *(const f32x4*)(xb + ((abase + 16) ^ ((arow & 7) << 5)));
            bf16x8 afrag;
            #pragma unroll
            for (int e = 0; e < 4; ++e) afrag[e] = (short)f2b(a0[e]);
            #pragma unroll
            for (int e = 0; e < 4; ++e) afrag[4 + e] = (short)f2b(a1[e]);
            __builtin_amdgcn_s_setprio(1);
            #pragma unroll
            for (int nt = 0; nt < 4; ++nt) {
                int brow = nt * 16 + l15;
                u32 bb = (u32)(brow * 128 + ks * 64 + g * 16);
                bf16x8 bfrag = *(const bf16x8*)(wb + (bb ^ ((brow & 7) << 4)));
                acc[nt] = __builtin_amdgcn_mfma_f32_16x16x32_bf16(afrag, bfrag, acc[nt], 0, 0, 0);
            }
            __builtin_amdgcn_s_setprio(0);
        }
        BAR();                                    // release buf[kt&1]
    }
    // epilogue: C col=l15(+16nt), row=g*4+r
    #pragma unroll
    for (int nt = 0; nt < 4; ++nt) {
        int dcol = nt * 16 + l15;
        #pragma unroll
        for (int r = 0; r < 4; ++r) {
            int row = row0 + w * 16 + g * 4 + r;
            float v = acc[nt][r];
            if (which == 0)      Qb[(size_t)row * DH + dcol] = f2b(v * 0.125f);
            else if (which == 1) Kb[(size_t)row * DH + dcol] = f2b(v);
            else { int bb2 = row >> 11, t = row & 2047;
                   Vt[(size_t)bb2 * DH * NT + (size_t)dcol * NT + t] = f2b(v); }
        }
    }
}

// ---------------------------------------------------------------------------
// Flash attention, KVBLK=128 (2x amortization of barriers/softmax/vmcnt vs
// R6's 64). QBLK=64 (4 waves x 16 q), swapped-operand in-register softmax.
// K_lds [128][64] rows 128B swz ^((r&7)<<4); V_lds [64][128] rows 256B swz
// ^((r&15)<<4); per-wave P [16 q][128 j] swz ^((l15&15)<<4).
// Chunking: nt128(qb) = (qb+2)>>1 tiles; nc = ceil(nt128/3); gx = 102.
// Only the last global tile masks: jl > delta + q_local, delta in {0,64}.
// ---------------------------------------------------------------------------
__global__ __launch_bounds__(256) void attn(
    const u16* __restrict__ Qb, const u16* __restrict__ Kb,
    const u16* __restrict__ Vt, u16* __restrict__ pOt, float* __restrict__ pml)
{
    __shared__ u16 k_lds[2][8192];    // 2 x 16 KB
    __shared__ u16 v_lds[2][8192];    // 2 x 16 KB
    __shared__ f32x4 p_lds[4][256];   // 4 x 4 KB

    const int tid = threadIdx.x, lane = tid & 63, w = tid >> 6;
    const int l15 = lane & 15, g = lane >> 4;
    const int b = blockIdx.y;

    // decode blockIdx.x -> (qb, chunk)
    int flat = blockIdx.x, qb = 0, nc, nt128;
    for (;;) {
        nt128 = (qb + 2) >> 1;
        nc = (nt128 + CHUNK3 - 1) / CHUNK3;
        if (flat < nc) break;
        flat -= nc; ++qb;
    }
    const int chunk = flat;
    const int t0 = chunk * CHUNK3;
    const int t1 = min(t0 + CHUNK3, nt128);
    const int tD = nt128 - 1;
    const int delta = qb * 64 - tD * 128;         // 0 (even qb) or 64 (odd)
    const int q0 = qb * 64;

    const u16* Qg = Qb + ((size_t)b * NT + q0 + w * 16) * DH;
    const u16* Kg = Kb + (size_t)b * NT * DH;
    const u16* Vg = Vt + (size_t)b * DH * NT;

    auto stage = [&](int t, int bi) {
        const int j0 = t * 128;
        #pragma unroll
        for (int i = 0; i < 4; ++i) {
            u32 D = (u32)(w * 4096 + i * 1024 + lane * 16);
            {   // K: [128 r][64 d], rows 128B
                u32 r = D >> 7, c = D & 127;
                u32 cs = c ^ ((r & 7) << 4);
                gld16(Kg + (size_t)(j0 + r) * DH + (cs >> 1),
                      (char*)&k_lds[bi][0] + w * 4096 + i * 1024);
            }
            {   // V: [64 d][128 j], rows 256B
                u32 r = D >> 8, c = D & 255;
                u32 cs = c ^ ((r & 15) << 4);
                gld16(Vg + (size_t)r * NT + j0 + (cs >> 1),
                      (char*)&v_lds[bi][0] + w * 4096 + i * 1024);
            }
        }
    };
    stage(t0, 0);

    // Q fragment (B-operand): col=l15 -> q = q0 + w*16 + l15, k over d
    bf16x8 qf[2];
    qf[0] = *(const bf16x8*)(Qg + l15 * DH + g * 8);
    qf[1] = *(const bf16x8*)(Qg + l15 * DH + 32 + g * 8);

    float m_run = -INFINITY, l_run = 0.f;
    f32x4 oacc[4];                    // O^T: d = nt*16+g*4+r, q = w*16+l15
    #pragma unroll
    for (int nt = 0; nt < 4; ++nt) oacc[nt] = {0.f, 0.f, 0.f, 0.f};

    char* pw = (char*)&p_lds[w][0];
    const u32 pswz = (u32)((l15 & 15) << 4);
    const int q_local = w * 16 + l15;

    for (int t = t0; t < t1; ++t) {
        const int cur = (t - t0) & 1;
        if (t + 1 < t1) {
            stage(t + 1, cur ^ 1);
            asm volatile("s_waitcnt vmcnt(8)" ::: "memory");
        } else {
            asm volatile("s_waitcnt vmcnt(0)" ::: "memory");
        }
        BAR();                                    // publish cur
        SBAR();
        const char* kb = (const char*)&k_lds[cur][0];
        const char* vb = (const char*)&v_lds[cur][0];

        // ---- QK^T swapped: sacc[f][r] = S[j = f*16+g*4+r][q], f=0..7 ----
        f32x4 sacc[8];
        #pragma unroll
        for (int f = 0; f < 8; ++f) sacc[f] = {0.f, 0.f, 0.f, 0.f};
        __builtin_amdgcn_s_setprio(1);
        #pragma unroll
        for (int ks = 0; ks < 2; ++ks) {
            #pragma unroll
            for (int f = 0; f < 8; ++f) {
                int arow = f * 16 + l15;          // j row in tile
                u32 aa = (u32)(arow * 128 + ks * 64 + g * 16);
                bf16x8 kf = *(const bf16x8*)(kb + (aa ^ ((arow & 7) << 4)));
                sacc[f] = __builtin_amdgcn_mfma_f32_16x16x32_bf16(kf, qf[ks], sacc[f], 0, 0, 0);
            }
        }
        __builtin_amdgcn_s_setprio(0);
        if (t == tD) {  // causal mask on the last tile only
            #pragma unroll
            for (int f = 0; f < 8; ++f)
                #pragma unroll
                for (int r = 0; r < 4; ++r)
                    if (f * 16 + g * 4 + r > delta + q_local) sacc[f][r] = -1e30f;
        }
        // ---- online softmax: 32 values/lane + xor16/xor32 ----
        float mx = -INFINITY;
        #pragma unroll
        for (int f = 0; f < 8; ++f) {
            float a = fmaxf(fmaxf(sacc[f][0], sacc[f][1]),
                            fmaxf(sacc[f][2], sacc[f][3]));
            mx = fmaxf(mx, a);
        }
        mx = fmaxf(mx, __shfl_xor(mx, 16));
        mx = fmaxf(mx, __shfl_xor(mx, 32));
        const float m_new = fmaxf(m_run, mx);
        const float alpha = __expf(m_run - m_new);
        float p[8][4];
        float ps = 0.f;
        #pragma unroll
        for (int f = 0; f < 8; ++f)
            #pragma unroll
            for (int r = 0; r < 4; ++r) {
                float pv = __expf(sacc[f][r] - m_new);
                p[f][r] = pv; ps += pv;
            }
        ps += __shfl_xor(ps, 16);
        ps += __shfl_xor(ps, 32);
        l_run = l_run * alpha + ps;
        m_run = m_new;
        #pragma unroll
        for (int nt = 0; nt < 4; ++nt)
            #pragma unroll
            for (int r = 0; r < 4; ++r) oacc[nt][r] *= alpha;

        // ---- P^T repack via per-wave LDS (same-wave, no barrier) ----
        #pragma unroll
        for (int f = 0; f < 8; ++f) {
            uint2 pk;
            pk.x = (u32)f2b(p[f][0]) | ((u32)f2b(p[f][1]) << 16);
            pk.y = (u32)f2b(p[f][2]) | ((u32)f2b(p[f][3]) << 16);
            u32 a = (u32)(l15 * 256 + f * 32 + g * 8) ^ pswz;
            *(uint2*)(pw + a) = pk;
        }
        bf16x8 pb_[4];
        #pragma unroll
        for (int ksj = 0; ksj < 4; ++ksj)
            pb_[ksj] = *(const bf16x8*)(pw + ((u32)(l15 * 256 + ksj * 64 + g * 16) ^ pswz));

        // ---- PV swapped: oacc[nt] += V[d][j] @ P^T[j][q], j = 0..127 ----
        __builtin_amdgcn_s_setprio(1);
        #pragma unroll
        for (int ksj = 0; ksj < 4; ++ksj) {
            #pragma unroll
            for (int nt = 0; nt < 4; ++nt) {
                int arow = nt * 16 + l15;          // d row
                u32 aa = (u32)(arow * 256 + ksj * 64 + g * 16);
                bf16x8 vf = *(const bf16x8*)(vb + (aa ^ ((arow & 15) << 4)));
                oacc[nt] = __builtin_amdgcn_mfma_f32_16x16x32_bf16(vf, pb_[ksj], oacc[nt], 0, 0, 0);
            }
        }
        __builtin_amdgcn_s_setprio(0);
        BAR();                                    // release cur
    }

    // write partials: O^T [d][q] bf16 (coalesced in l15), m/l per q
    const int slot = (b * 32 + qb) * SLOTS + chunk;
    u16* Op = pOt + (size_t)slot * 4096;
    #pragma unroll
    for (int nt = 0; nt < 4; ++nt)
        #pragma unroll
        for (int r = 0; r < 4; ++r)
            Op[(nt * 16 + g * 4 + r) * 64 + w * 16 + l15] = f2b(oacc[nt][r]);
    if (g == 0) {
        float* mlp = pml + (size_t)slot * 128;
        mlp[(w * 16 + l15) * 2]     = m_run;
        mlp[(w * 16 + l15) * 2 + 1] = l_run;
    }
}

// ---------------------------------------------------------------------------
// Merge <=SLOTS transposed partials per (b,qb); LDS transpose; fp32 out [q][d].
// grid = NB*32 blocks. nc matches attn decode.
// ---------------------------------------------------------------------------
__global__ __launch_bounds__(256) void merge(
    const u16* __restrict__ pOt, const float* __restrict__ pml,
    float* __restrict__ out)
{
    __shared__ float tl[64][65];
    const int bq = blockIdx.x;             // b*32 + qb
    const int b = bq >> 5, qb = bq & 31;
    const int nt128 = (qb + 2) >> 1;
    const int nc = (nt128 + CHUNK3 - 1) / CHUNK3;
    const int base = bq * SLOTS;
    const int q = threadIdx.x & 63, ds = threadIdx.x >> 6;

    float m = -INFINITY;
    for (int c = 0; c < nc; ++c)
        m = fmaxf(m, pml[(size_t)(base + c) * 128 + q * 2]);
    float lsum = 0.f;
    float acc[16];
    #pragma unroll
    for (int i = 0; i < 16; ++i) acc[i] = 0.f;
    for (int c = 0; c < nc; ++c) {
        const float mc = pml[(size_t)(base + c) * 128 + q * 2];
        const float lc = pml[(size_t)(base + c) * 128 + q * 2 + 1];
        const float wc = __expf(mc - m);
        lsum += wc * lc;
        const u16* Op = pOt + (size_t)(base + c) * 4096;
        #pragma unroll
        for (int i = 0; i < 16; ++i)
            acc[i] += wc * b2f(Op[(ds * 16 + i) * 64 + q]);
    }
    const float inv = 1.f / lsum;
    #pragma unroll
    for (int i = 0; i < 16; ++i) tl[q][ds * 16 + i] = acc[i] * inv;
    __syncthreads();
    const int q2 = threadIdx.x >> 2, dc = threadIdx.x & 3;
    float* orow = out + ((size_t)b * NT + qb * 64 + q2) * 64 + dc * 16;
    #pragma unroll
    for (int j4 = 0; j4 < 4; ++j4) {
        float4 v = { tl[q2][dc * 16 + j4 * 4 + 0], tl[q2][dc * 16 + j4 * 4 + 1],
                     tl[q2][dc * 16 + j4 * 4 + 2], tl[q2][dc * 16 + j4 * 4 + 3] };
        *(float4*)&orow[j4 * 4] = v;
    }
}

extern "C" void kernel_launch(void* const* d_in, const int* in_sizes, int n_in,
                              void* d_out, int out_size, void* d_ws, size_t ws_size,
                              hipStream_t stream) {
    const float* x  = (const float*)d_in[0];
    const float* WQ = (const float*)d_in[1];
    const float* WK = (const float*)d_in[2];
    const float* WV = (const float*)d_in[3];
    float* out = (float*)d_out;

    char* ws = (char*)d_ws;
    u16*   Qb  = (u16*)ws;                          // 1 MB
    u16*   Kb  = (u16*)(ws + 1048576);              // 1 MB
    u16*   Vt  = (u16*)(ws + 2097152);              // 1 MB
    u16*   Wt  = (u16*)(ws + 3145728);              // 384 KB
    u16*   pOt = (u16*)(ws + 3538944);              // 768 slots * 8 KB = 6 MB
    float* pml = (float*)(ws + 3538944 + 6291456);  // 384 KB

    // attn grid.x = sum over qb of ceil(((qb+2)>>1)/3) = 102
    wt_conv<<<dim3(16, 3), 256, 0, stream>>>(WQ, WK, WV, Wt);
    qkv_gemm<<<dim3(128, 3), 256, 0, stream>>>(x, Wt, Qb, Kb, Vt);
    attn<<<dim3(102, NB), 256, 0, stream>>>(Qb, Kb, Vt, pOt, pml);
    merge<<<NB * 32, 256, 0, stream>>>(pOt, pml, out);
}

// Round 15
// 42.788 us; speedup vs baseline: 8.3891x; 1.0001x over previous
//
#include <hip/hip_runtime.h>
#include <hip/hip_bf16.h>

#define NB 4
#define NT 2048
#define DM 1024
#define DH 64
#define CHUNK3 3          // KV chunk in units of 128-key tiles
#define SLOTS 6

typedef __attribute__((ext_vector_type(8))) short bf16x8;
typedef __attribute__((ext_vector_type(4))) float f32x4;
typedef unsigned short u16;
typedef unsigned int u32;

static __device__ __forceinline__ u16 f2b(float f) {
    __hip_bfloat16 h = __float2bfloat16(f);
    return __builtin_bit_cast(u16, h);
}
static __device__ __forceinline__ float b2f(u16 h) {
    return __builtin_bit_cast(float, (u32)h << 16);
}
// global -> LDS DMA, 16B per lane. lds ptr must be wave-uniform (HW adds lane*16).
static __device__ __forceinline__ void gld16(const void* g, void* l) {
    __builtin_amdgcn_global_load_lds((const __attribute__((address_space(1))) void*)g,
                                     (__attribute__((address_space(3))) void*)l, 16, 0, 0);
}
#define BAR() __builtin_amdgcn_s_barrier()
#define SBAR() __builtin_amdgcn_sched_barrier(0)

// ---------------------------------------------------------------------------
// Wt[which][d][k] bf16 <- W[k][d] fp32, via LDS transpose. grid (16, 3)
// ---------------------------------------------------------------------------
__global__ __launch_bounds__(256) void wt_conv(
    const float* __restrict__ WQ, const float* __restrict__ WK,
    const float* __restrict__ WV, u16* __restrict__ wt)
{
    __shared__ u16 tl[64][68];
    const int which = blockIdx.y, kt = blockIdx.x;
    const float* W = (which == 0) ? WQ : (which == 1) ? WK : WV;
    #pragma unroll
    for (int i = 0; i < 4; ++i) {
        int r = (threadIdx.x >> 4) + i * 16;         // k-local
        int c = (threadIdx.x & 15) * 4;              // d
        float4 v = *(const float4*)&W[(size_t)(kt * 64 + r) * DH + c];
        tl[r][c] = f2b(v.x); tl[r][c + 1] = f2b(v.y);
        tl[r][c + 2] = f2b(v.z); tl[r][c + 3] = f2b(v.w);
    }
    __syncthreads();
    int d = threadIdx.x >> 2, kc = (threadIdx.x & 3) * 16;
    u16 buf[16];
    #pragma unroll
    for (int j = 0; j < 16; ++j) buf[j] = tl[kc + j][d];
    u16* dst = wt + which * 65536 + d * 1024 + kt * 64 + kc;
    *(uint4*)dst = *(uint4*)&buf[0];
    *(uint4*)(dst + 8) = *(uint4*)&buf[8];
}

// ---------------------------------------------------------------------------
// QKV GEMM, bf16-x staging. grid (128, 3): 64-row tile x one of Q/K/V.
// x: global fp32 -> regs (4 dwordx4/thread, issued 1 step ahead) -> cvt bf16
// -> ds_write swizzled (8KB/buffer, same layout as W). W: gld16 DMA.
// Pipeline per iter: vmcnt(2) [x-regs ready] -> cvt+write -> issue x(s+1)+
// W(s+1) -> vmcnt(6) [W(s) landed] -> lgkmcnt(0) -> BAR -> compute -> BAR.
// LDS 32KB total -> 5 blocks/CU. Per step: 10 ds_read_b128, 8 MFMA, no f2b
// in the compute phase.
// ---------------------------------------------------------------------------
__global__ __launch_bounds__(256) void qkv_gemm(
    const float* __restrict__ x, const u16* __restrict__ wt,
    u16* __restrict__ Qb, u16* __restrict__ Kb, u16* __restrict__ Vt)
{
    __shared__ u16 xbuf[2][4096];     // [64 r][64 k] bf16, rows 128B, ^((r&7)<<4)
    __shared__ u16 wsm[2][4096];      // same layout
    const int tid = threadIdx.x, lane = tid & 63, w = tid >> 6;
    const int l15 = lane & 15, g = lane >> 4;
    const int row0 = blockIdx.x * 64;
    const int which = blockIdx.y;
    const u16* Wg = wt + which * 65536;

    // x reg-staging geometry: thread -> row xr_, 16-col chunk xc0
    const int xr_ = tid >> 2, xc4 = tid & 3;
    const float* xsrc = x + (size_t)(row0 + xr_) * DM + xc4 * 16;
    const u32 xsw = (u32)((xr_ & 7) << 4);
    const u32 xa0 = (u32)(xr_ * 128 + xc4 * 32) ^ xsw;
    const u32 xa1 = (u32)(xr_ * 128 + xc4 * 32 + 16) ^ xsw;

    f32x4 xv[4];
    auto xload = [&](int kt) {
        const float* p = xsrc + kt * 64;
        xv[0] = *(const f32x4*)(p);
        xv[1] = *(const f32x4*)(p + 4);
        xv[2] = *(const f32x4*)(p + 8);
        xv[3] = *(const f32x4*)(p + 12);
    };
    auto stageW = [&](int kt, int bi) {
        #pragma unroll
        for (int i = 0; i < 2; ++i) {
            u32 D = (u32)(w * 2048 + i * 1024 + lane * 16);
            u32 r = D >> 7, c = D & 127;
            u32 cs = c ^ ((r & 7) << 4);
            gld16(Wg + (size_t)r * 1024 + kt * 64 + (cs >> 1),
                  (char*)&wsm[bi][0] + w * 2048 + i * 1024);
        }
    };

    f32x4 acc[4];
    #pragma unroll
    for (int i = 0; i < 4; ++i) acc[i] = {0.f, 0.f, 0.f, 0.f};

    xload(0);                                     // 4 VMEM
    stageW(0, 0);                                 // 2 VMEM
    const int arow = w * 16 + l15;
    const u32 asw = (u32)((arow & 7) << 4);

    #pragma unroll
    for (int kt = 0; kt < 16; ++kt) {
        const int cur = kt & 1;
        asm volatile("s_waitcnt vmcnt(2)" ::: "memory");   // x(kt) regs ready
        {   // cvt fp32 -> bf16, swizzled ds_write (2 x b128)
            u16 tmp[16];
            #pragma unroll
            for (int i = 0; i < 4; ++i)
                #pragma unroll
                for (int j = 0; j < 4; ++j) tmp[i * 4 + j] = f2b(xv[i][j]);
            *(uint4*)((char*)&xbuf[cur][0] + xa0) = *(uint4*)&tmp[0];
            *(uint4*)((char*)&xbuf[cur][0] + xa1) = *(uint4*)&tmp[8];
        }
        if (kt < 15) {
            xload(kt + 1);                        // 4 VMEM (oldest of new 6)
            stageW(kt + 1, cur ^ 1);              // 2 VMEM
            asm volatile("s_waitcnt vmcnt(6)" ::: "memory");   // W(kt) landed
        } else {
            asm volatile("s_waitcnt vmcnt(0)" ::: "memory");
        }
        asm volatile("s_waitcnt lgkmcnt(0)" ::: "memory");     // x writes done
        BAR();                                    // publish buf[cur]
        SBAR();
        const char* xb = (const char*)&xbuf[cur][0];
        const char* wb = (const char*)&wsm[cur][0];
        #pragma unroll
        for (int ks = 0; ks < 2; ++ks) {
            bf16x8 afrag = *(const bf16x8*)(xb + ((u32)(arow * 128 + ks * 64 + g * 16) ^ asw));
            __builtin_amdgcn_s_setprio(1);
            #pragma unroll
            for (int nt = 0; nt < 4; ++nt) {
                int brow = nt * 16 + l15;
                u32 bb = (u32)(brow * 128 + ks * 64 + g * 16);
                bf16x8 bfrag = *(const bf16x8*)(wb + (bb ^ ((brow & 7) << 4)));
                acc[nt] = __builtin_amdgcn_mfma_f32_16x16x32_bf16(afrag, bfrag, acc[nt], 0, 0, 0);
            }
            __builtin_amdgcn_s_setprio(0);
        }
        BAR();                                    // release buf[cur]
    }
    // epilogue: C col=l15(+16nt), row=g*4+r
    #pragma unroll
    for (int nt = 0; nt < 4; ++nt) {
        int dcol = nt * 16 + l15;
        #pragma unroll
        for (int r = 0; r < 4; ++r) {
            int row = row0 + w * 16 + g * 4 + r;
            float v = acc[nt][r];
            if (which == 0)      Qb[(size_t)row * DH + dcol] = f2b(v * 0.125f);
            else if (which == 1) Kb[(size_t)row * DH + dcol] = f2b(v);
            else { int bb2 = row >> 11, t = row & 2047;
                   Vt[(size_t)bb2 * DH * NT + (size_t)dcol * NT + t] = f2b(v); }
        }
    }
}

// ---------------------------------------------------------------------------
// Flash attention (R14 champion body, verbatim). KVBLK=128, QBLK=64.
// ---------------------------------------------------------------------------
__global__ __launch_bounds__(256) void attn(
    const u16* __restrict__ Qb, const u16* __restrict__ Kb,
    const u16* __restrict__ Vt, u16* __restrict__ pOt, float* __restrict__ pml)
{
    __shared__ u16 k_lds[2][8192];    // 2 x 16 KB
    __shared__ u16 v_lds[2][8192];    // 2 x 16 KB
    __shared__ f32x4 p_lds[4][256];   // 4 x 4 KB

    const int tid = threadIdx.x, lane = tid & 63, w = tid >> 6;
    const int l15 = lane & 15, g = lane >> 4;
    const int b = blockIdx.y;

    // decode blockIdx.x -> (qb, chunk)
    int flat = blockIdx.x, qb = 0, nc, nt128;
    for (;;) {
        nt128 = (qb + 2) >> 1;
        nc = (nt128 + CHUNK3 - 1) / CHUNK3;
        if (flat < nc) break;
        flat -= nc; ++qb;
    }
    const int chunk = flat;
    const int t0 = chunk * CHUNK3;
    const int t1 = min(t0 + CHUNK3, nt128);
    const int tD = nt128 - 1;
    const int delta = qb * 64 - tD * 128;         // 0 (even qb) or 64 (odd)
    const int q0 = qb * 64;

    const u16* Qg = Qb + ((size_t)b * NT + q0 + w * 16) * DH;
    const u16* Kg = Kb + (size_t)b * NT * DH;
    const u16* Vg = Vt + (size_t)b * DH * NT;

    auto stage = [&](int t, int bi) {
        const int j0 = t * 128;
        #pragma unroll
        for (int i = 0; i < 4; ++i) {
            u32 D = (u32)(w * 4096 + i * 1024 + lane * 16);
            {   // K: [128 r][64 d], rows 128B
                u32 r = D >> 7, c = D & 127;
                u32 cs = c ^ ((r & 7) << 4);
                gld16(Kg + (size_t)(j0 + r) * DH + (cs >> 1),
                      (char*)&k_lds[bi][0] + w * 4096 + i * 1024);
            }
            {   // V: [64 d][128 j], rows 256B
                u32 r = D >> 8, c = D & 255;
                u32 cs = c ^ ((r & 15) << 4);
                gld16(Vg + (size_t)r * NT + j0 + (cs >> 1),
                      (char*)&v_lds[bi][0] + w * 4096 + i * 1024);
            }
        }
    };
    stage(t0, 0);

    // Q fragment (B-operand): col=l15 -> q = q0 + w*16 + l15, k over d
    bf16x8 qf[2];
    qf[0] = *(const bf16x8*)(Qg + l15 * DH + g * 8);
    qf[1] = *(const bf16x8*)(Qg + l15 * DH + 32 + g * 8);

    float m_run = -INFINITY, l_run = 0.f;
    f32x4 oacc[4];                    // O^T: d = nt*16+g*4+r, q = w*16+l15
    #pragma unroll
    for (int nt = 0; nt < 4; ++nt) oacc[nt] = {0.f, 0.f, 0.f, 0.f};

    char* pw = (char*)&p_lds[w][0];
    const u32 pswz = (u32)((l15 & 15) << 4);
    const int q_local = w * 16 + l15;

    for (int t = t0; t < t1; ++t) {
        const int cur = (t - t0) & 1;
        if (t + 1 < t1) {
            stage(t + 1, cur ^ 1);
            asm volatile("s_waitcnt vmcnt(8)" ::: "memory");
        } else {
            asm volatile("s_waitcnt vmcnt(0)" ::: "memory");
        }
        BAR();                                    // publish cur
        SBAR();
        const char* kb = (const char*)&k_lds[cur][0];
        const char* vb = (const char*)&v_lds[cur][0];

        // ---- QK^T swapped: sacc[f][r] = S[j = f*16+g*4+r][q], f=0..7 ----
        f32x4 sacc[8];
        #pragma unroll
        for (int f = 0; f < 8; ++f) sacc[f] = {0.f, 0.f, 0.f, 0.f};
        __builtin_amdgcn_s_setprio(1);
        #pragma unroll
        for (int ks = 0; ks < 2; ++ks) {
            #pragma unroll
            for (int f = 0; f < 8; ++f) {
                int arow = f * 16 + l15;          // j row in tile
                u32 aa = (u32)(arow * 128 + ks * 64 + g * 16);
                bf16x8 kf = *(const bf16x8*)(kb + (aa ^ ((arow & 7) << 4)));
                sacc[f] = __builtin_amdgcn_mfma_f32_16x16x32_bf16(kf, qf[ks], sacc[f], 0, 0, 0);
            }
        }
        __builtin_amdgcn_s_setprio(0);
        if (t == tD) {  // causal mask on the last tile only
            #pragma unroll
            for (int f = 0; f < 8; ++f)
                #pragma unroll
                for (int r = 0; r < 4; ++r)
                    if (f * 16 + g * 4 + r > delta + q_local) sacc[f][r] = -1e30f;
        }
        // ---- online softmax: 32 values/lane + xor16/xor32 ----
        float mx = -INFINITY;
        #pragma unroll
        for (int f = 0; f < 8; ++f) {
            float a = fmaxf(fmaxf(sacc[f][0], sacc[f][1]),
                            fmaxf(sacc[f][2], sacc[f][3]));
            mx = fmaxf(mx, a);
        }
        mx = fmaxf(mx, __shfl_xor(mx, 16));
        mx = fmaxf(mx, __shfl_xor(mx, 32));
        const float m_new = fmaxf(m_run, mx);
        const float alpha = __expf(m_run - m_new);
        float p[8][4];
        float ps = 0.f;
        #pragma unroll
        for (int f = 0; f < 8; ++f)
            #pragma unroll
            for (int r = 0; r < 4; ++r) {
                float pv = __expf(sacc[f][r] - m_new);
                p[f][r] = pv; ps += pv;
            }
        ps += __shfl_xor(ps, 16);
        ps += __shfl_xor(ps, 32);
        l_run = l_run * alpha + ps;
        m_run = m_new;
        #pragma unroll
        for (int nt = 0; nt < 4; ++nt)
            #pragma unroll
            for (int r = 0; r < 4; ++r) oacc[nt][r] *= alpha;

        // ---- P^T repack via per-wave LDS (same-wave, no barrier) ----
        #pragma unroll
        for (int f = 0; f < 8; ++f) {
            uint2 pk;
            pk.x = (u32)f2b(p[f][0]) | ((u32)f2b(p[f][1]) << 16);
            pk.y = (u32)f2b(p[f][2]) | ((u32)f2b(p[f][3]) << 16);
            u32 a = (u32)(l15 * 256 + f * 32 + g * 8) ^ pswz;
            *(uint2*)(pw + a) = pk;
        }
        bf16x8 pb_[4];
        #pragma unroll
        for (int ksj = 0; ksj < 4; ++ksj)
            pb_[ksj] = *(const bf16x8*)(pw + ((u32)(l15 * 256 + ksj * 64 + g * 16) ^ pswz));

        // ---- PV swapped: oacc[nt] += V[d][j] @ P^T[j][q], j = 0..127 ----
        __builtin_amdgcn_s_setprio(1);
        #pragma unroll
        for (int ksj = 0; ksj < 4; ++ksj) {
            #pragma unroll
            for (int nt = 0; nt < 4; ++nt) {
                int arow = nt * 16 + l15;          // d row
                u32 aa = (u32)(arow * 256 + ksj * 64 + g * 16);
                bf16x8 vf = *(const bf16x8*)(vb + (aa ^ ((arow & 15) << 4)));
                oacc[nt] = __builtin_amdgcn_mfma_f32_16x16x32_bf16(vf, pb_[ksj], oacc[nt], 0, 0, 0);
            }
        }
        __builtin_amdgcn_s_setprio(0);
        BAR();                                    // release cur
    }

    // write partials: O^T [d][q] bf16 (coalesced in l15), m/l per q
    const int slot = (b * 32 + qb) * SLOTS + chunk;
    u16* Op = pOt + (size_t)slot * 4096;
    #pragma unroll
    for (int nt = 0; nt < 4; ++nt)
        #pragma unroll
        for (int r = 0; r < 4; ++r)
            Op[(nt * 16 + g * 4 + r) * 64 + w * 16 + l15] = f2b(oacc[nt][r]);
    if (g == 0) {
        float* mlp = pml + (size_t)slot * 128;
        mlp[(w * 16 + l15) * 2]     = m_run;
        mlp[(w * 16 + l15) * 2 + 1] = l_run;
    }
}

// ---------------------------------------------------------------------------
// Merge <=SLOTS transposed partials per (b,qb); LDS transpose; fp32 out [q][d].
// grid = NB*32 blocks. nc matches attn decode.
// ---------------------------------------------------------------------------
__global__ __launch_bounds__(256) void merge(
    const u16* __restrict__ pOt, const float* __restrict__ pml,
    float* __restrict__ out)
{
    __shared__ float tl[64][65];
    const int bq = blockIdx.x;             // b*32 + qb
    const int b = bq >> 5, qb = bq & 31;
    const int nt128 = (qb + 2) >> 1;
    const int nc = (nt128 + CHUNK3 - 1) / CHUNK3;
    const int base = bq * SLOTS;
    const int q = threadIdx.x & 63, ds = threadIdx.x >> 6;

    float m = -INFINITY;
    for (int c = 0; c < nc; ++c)
        m = fmaxf(m, pml[(size_t)(base + c) * 128 + q * 2]);
    float lsum = 0.f;
    float acc[16];
    #pragma unroll
    for (int i = 0; i < 16; ++i) acc[i] = 0.f;
    for (int c = 0; c < nc; ++c) {
        const float mc = pml[(size_t)(base + c) * 128 + q * 2];
        const float lc = pml[(size_t)(base + c) * 128 + q * 2 + 1];
        const float wc = __expf(mc - m);
        lsum += wc * lc;
        const u16* Op = pOt + (size_t)(base + c) * 4096;
        #pragma unroll
        for (int i = 0; i < 16; ++i)
            acc[i] += wc * b2f(Op[(ds * 16 + i) * 64 + q]);
    }
    const float inv = 1.f / lsum;
    #pragma unroll
    for (int i = 0; i < 16; ++i) tl[q][ds * 16 + i] = acc[i] * inv;
    __syncthreads();
    const int q2 = threadIdx.x >> 2, dc = threadIdx.x & 3;
    float* orow = out + ((size_t)b * NT + qb * 64 + q2) * 64 + dc * 16;
    #pragma unroll
    for (int j4 = 0; j4 < 4; ++j4) {
        float4 v = { tl[q2][dc * 16 + j4 * 4 + 0], tl[q2][dc * 16 + j4 * 4 + 1],
                     tl[q2][dc * 16 + j4 * 4 + 2], tl[q2][dc * 16 + j4 * 4 + 3] };
        *(float4*)&orow[j4 * 4] = v;
    }
}

extern "C" void kernel_launch(void* const* d_in, const int* in_sizes, int n_in,
                              void* d_out, int out_size, void* d_ws, size_t ws_size,
                              hipStream_t stream) {
    const float* x  = (const float*)d_in[0];
    const float* WQ = (const float*)d_in[1];
    const float* WK = (const float*)d_in[2];
    const float* WV = (const float*)d_in[3];
    float* out = (float*)d_out;

    char* ws = (char*)d_ws;
    u16*   Qb  = (u16*)ws;                          // 1 MB
    u16*   Kb  = (u16*)(ws + 1048576);              // 1 MB
    u16*   Vt  = (u16*)(ws + 2097152);              // 1 MB
    u16*   Wt  = (u16*)(ws + 3145728);              // 384 KB
    u16*   pOt = (u16*)(ws + 3538944);              // 768 slots * 8 KB = 6 MB
    float* pml = (float*)(ws + 3538944 + 6291456);  // 384 KB

    // attn grid.x = sum over qb of ceil(((qb+2)>>1)/3) = 102
    wt_conv<<<dim3(16, 3), 256, 0, stream>>>(WQ, WK, WV, Wt);
    qkv_gemm<<<dim3(128, 3), 256, 0, stream>>>(x, Wt, Qb, Kb, Vt);
    attn<<<dim3(102, NB), 256, 0, stream>>>(Qb, Kb, Vt, pOt, pml);
    merge<<<NB * 32, 256, 0, stream>>>(pOt, pml, out);
}